// Round 1
// baseline (286.607 us; speedup 1.0000x reference)
//
#include <hip/hip_runtime.h>
#include <stdint.h>

// B=2, T=2048, C=1024, H=16, HD=64
// q/k/v ws layout: [3][B*H=32][T=2048][HD=64] bf16

typedef short bf16x8 __attribute__((ext_vector_type(8)));
typedef float f32x4 __attribute__((ext_vector_type(4)));

__device__ inline unsigned short f2bf(float f) {
  union { float f; uint32_t u; } v; v.f = f;
  uint32_t u = v.u;
  u += 0x7FFFu + ((u >> 16) & 1u);   // round-to-nearest-even
  return (unsigned short)(u >> 16);
}

// ---------- cast fp32 -> bf16 (vectorized x4) ----------
__global__ __launch_bounds__(256) void cast_bf16_kernel(
    const float* __restrict__ in, unsigned short* __restrict__ out, int n4) {
  int i = blockIdx.x * 256 + threadIdx.x;
  if (i >= n4) return;
  float4 f = reinterpret_cast<const float4*>(in)[i];
  ushort4 o;
  o.x = f2bf(f.x); o.y = f2bf(f.y); o.z = f2bf(f.z); o.w = f2bf(f.w);
  reinterpret_cast<ushort4*>(out)[i] = o;
}

// ---------- transpose [R,Cn] fp32 -> [Cn,R] bf16 ----------
__global__ void transpose_cast_kernel(
    const float* __restrict__ in, unsigned short* __restrict__ out, int R, int Cn) {
  __shared__ float tile[32][33];
  int bx = blockIdx.x * 32, by = blockIdx.y * 32;
  int tx = threadIdx.x, ty = threadIdx.y;  // block (32,8)
  #pragma unroll
  for (int i = 0; i < 32; i += 8)
    tile[ty + i][tx] = in[(size_t)(by + ty + i) * Cn + bx + tx];
  __syncthreads();
  #pragma unroll
  for (int i = 0; i < 32; i += 8)
    out[(size_t)(bx + ty + i) * R + by + tx] = f2bf(tile[tx][ty + i]);
}

// ---------- bf16 MFMA GEMM: C[M,N] = A[M,K] * Bt[N,K]^T + bias ----------
// mode 0: write fp32 to out [M,N]
// mode 1: QKV scatter: col -> (sel,h,d), row -> (b,t); q scaled by 0.125; bf16 out
__global__ __launch_bounds__(256) void gemm_bt_kernel(
    const unsigned short* __restrict__ A,
    const unsigned short* __restrict__ Bt,
    const float* __restrict__ bias,
    void* __restrict__ outp,
    int M, int N, int K, int mode) {
  __shared__ unsigned short As[128][40];  // +8 pad: conflict-free b128 frag reads
  __shared__ unsigned short Bs[128][40];
  const int t = threadIdx.x;
  const int wave = t >> 6, lane = t & 63;
  const int L = lane & 15, quad = lane >> 4;
  const int wm = (wave >> 1) * 64, wn = (wave & 1) * 64;
  const int m0 = blockIdx.y * 128, n0 = blockIdx.x * 128;

  f32x4 acc[4][4] = {};

  for (int k0 = 0; k0 < K; k0 += 32) {
    __syncthreads();
    #pragma unroll
    for (int i = 0; i < 2; ++i) {
      int c = t + i * 256;            // 512 chunks of 8 bf16 per tile
      int row = c >> 2, kc = c & 3;
      *reinterpret_cast<uint4*>(&As[row][kc * 8]) =
          *reinterpret_cast<const uint4*>(A + (size_t)(m0 + row) * K + k0 + kc * 8);
      *reinterpret_cast<uint4*>(&Bs[row][kc * 8]) =
          *reinterpret_cast<const uint4*>(Bt + (size_t)(n0 + row) * K + k0 + kc * 8);
    }
    __syncthreads();
    bf16x8 af[4], bf[4];
    #pragma unroll
    for (int mt = 0; mt < 4; ++mt)
      af[mt] = *reinterpret_cast<const bf16x8*>(&As[wm + mt * 16 + L][quad * 8]);
    #pragma unroll
    for (int nt = 0; nt < 4; ++nt)
      bf[nt] = *reinterpret_cast<const bf16x8*>(&Bs[wn + nt * 16 + L][quad * 8]);
    #pragma unroll
    for (int mt = 0; mt < 4; ++mt)
      #pragma unroll
      for (int nt = 0; nt < 4; ++nt)
        acc[mt][nt] = __builtin_amdgcn_mfma_f32_16x16x32_bf16(af[mt], bf[nt], acc[mt][nt], 0, 0, 0);
  }

  if (mode == 0) {
    float* out = (float*)outp;
    #pragma unroll
    for (int mt = 0; mt < 4; ++mt)
      #pragma unroll
      for (int nt = 0; nt < 4; ++nt) {
        int col = n0 + wn + nt * 16 + L;
        float b = bias[col];
        #pragma unroll
        for (int r = 0; r < 4; ++r) {
          int row = m0 + wm + mt * 16 + quad * 4 + r;
          out[(size_t)row * N + col] = acc[mt][nt][r] + b;
        }
      }
  } else {
    unsigned short* qkv = (unsigned short*)outp;  // [3][32][2048][64]
    #pragma unroll
    for (int mt = 0; mt < 4; ++mt)
      #pragma unroll
      for (int nt = 0; nt < 4; ++nt) {
        int col = n0 + wn + nt * 16 + L;          // 0..3071
        int sel = col >> 10, cc = col & 1023;
        int h = cc >> 6, d = cc & 63;
        float b = bias[col];
        float sc = (sel == 0) ? 0.125f : 1.0f;    // fold 1/sqrt(64) into q
        #pragma unroll
        for (int r = 0; r < 4; ++r) {
          int row = m0 + wm + mt * 16 + quad * 4 + r;  // 0..4095
          int bb = row >> 11, tt = row & 2047;
          float val = (acc[mt][nt][r] + b) * sc;
          qkv[(((size_t)sel * 32 + (size_t)(bb * 16 + h)) * 2048 + tt) * 64 + d] = f2bf(val);
        }
      }
  }
}

// ---------- flash attention: block = (128 q-rows, one (b,h)); 4 waves x 32 rows ----------
__global__ __launch_bounds__(256) void attn_kernel(
    const unsigned short* __restrict__ qkv, unsigned short* __restrict__ y) {
  __shared__ unsigned short Ks[64][72];      // [key][d], pad 72
  __shared__ unsigned short Vt[64][72];      // [d][key], pad 72
  __shared__ unsigned short Ps[4][32][72];   // per-wave P, [row][key], pad 72

  const int t = threadIdx.x;
  const int wave = t >> 6, lane = t & 63;
  const int L = lane & 15, quad = lane >> 4;
  const int bh = blockIdx.y;
  const int qbase = blockIdx.x * 128;
  const int qrow0 = qbase + wave * 32;

  const unsigned short* qb = qkv + ((size_t)bh * 2048) * 64;
  const unsigned short* kb = qkv + ((size_t)(32 + bh) * 2048) * 64;
  const unsigned short* vb = qkv + ((size_t)(64 + bh) * 2048) * 64;

  // Q fragments live in registers for the whole kernel (A-layout, direct from global)
  bf16x8 qf[2][2];
  #pragma unroll
  for (int mt = 0; mt < 2; ++mt)
    #pragma unroll
    for (int half = 0; half < 2; ++half)
      qf[mt][half] = *reinterpret_cast<const bf16x8*>(
          qb + (size_t)(qrow0 + mt * 16 + L) * 64 + half * 32 + quad * 8);

  f32x4 o[2][4] = {};
  float m_i[2][4], l_i[2][4];
  #pragma unroll
  for (int mt = 0; mt < 2; ++mt)
    #pragma unroll
    for (int r = 0; r < 4; ++r) { m_i[mt][r] = -1e30f; l_i[mt][r] = 0.f; }

  const int kend = qbase + 128;
  for (int kbase = 0; kbase < kend; kbase += 64) {
    __syncthreads();
    // stage K tile [64 keys][64 d]
    #pragma unroll
    for (int i = 0; i < 2; ++i) {
      int c = t + i * 256;
      int key = c >> 3, dc = c & 7;
      *reinterpret_cast<uint4*>(&Ks[key][dc * 8]) =
          *reinterpret_cast<const uint4*>(kb + (size_t)(kbase + key) * 64 + dc * 8);
    }
    // stage V transposed: Vt[d][key]
    {
      int key = t & 63, dc0 = t >> 6;
      #pragma unroll
      for (int i = 0; i < 2; ++i) {
        int dc = dc0 + i * 4;
        uint4 raw = *reinterpret_cast<const uint4*>(vb + (size_t)(kbase + key) * 64 + dc * 8);
        const unsigned short* pr = reinterpret_cast<const unsigned short*>(&raw);
        #pragma unroll
        for (int j = 0; j < 8; ++j) Vt[dc * 8 + j][key] = pr[j];
      }
    }
    __syncthreads();

    // S = Q K^T  (scale already folded into q)
    f32x4 s[2][4] = {};
    bf16x8 kf[4][2];
    #pragma unroll
    for (int nt = 0; nt < 4; ++nt) {
      kf[nt][0] = *reinterpret_cast<const bf16x8*>(&Ks[nt * 16 + L][quad * 8]);
      kf[nt][1] = *reinterpret_cast<const bf16x8*>(&Ks[nt * 16 + L][32 + quad * 8]);
    }
    #pragma unroll
    for (int mt = 0; mt < 2; ++mt)
      #pragma unroll
      for (int nt = 0; nt < 4; ++nt) {
        s[mt][nt] = __builtin_amdgcn_mfma_f32_16x16x32_bf16(qf[mt][0], kf[nt][0], s[mt][nt], 0, 0, 0);
        s[mt][nt] = __builtin_amdgcn_mfma_f32_16x16x32_bf16(qf[mt][1], kf[nt][1], s[mt][nt], 0, 0, 0);
      }

    // causal mask (only tiles that can cross the diagonal for this wave)
    if (kbase + 63 > qrow0) {
      #pragma unroll
      for (int mt = 0; mt < 2; ++mt)
        #pragma unroll
        for (int nt = 0; nt < 4; ++nt) {
          int key = kbase + nt * 16 + L;
          #pragma unroll
          for (int r = 0; r < 4; ++r) {
            int row = qrow0 + mt * 16 + quad * 4 + r;
            if (key > row) s[mt][nt][r] = -1e30f;
          }
        }
    }

    // online softmax per 16-row tile; row r lives in the 16 lanes of this quad
    #pragma unroll
    for (int mt = 0; mt < 2; ++mt) {
      float mx[4], mnew[4], alpha[4], rs[4];
      #pragma unroll
      for (int r = 0; r < 4; ++r) {
        float v = s[mt][0][r];
        #pragma unroll
        for (int nt = 1; nt < 4; ++nt) v = fmaxf(v, s[mt][nt][r]);
        #pragma unroll
        for (int off = 1; off < 16; off <<= 1) v = fmaxf(v, __shfl_xor(v, off, 64));
        mx[r] = v;
      }
      #pragma unroll
      for (int r = 0; r < 4; ++r) {
        mnew[r] = fmaxf(m_i[mt][r], mx[r]);
        alpha[r] = __expf(m_i[mt][r] - mnew[r]);
        m_i[mt][r] = mnew[r];
        rs[r] = 0.f;
      }
      #pragma unroll
      for (int nt = 0; nt < 4; ++nt)
        #pragma unroll
        for (int r = 0; r < 4; ++r) {
          float p = __expf(s[mt][nt][r] - mnew[r]);
          s[mt][nt][r] = p;
          rs[r] += p;
        }
      #pragma unroll
      for (int r = 0; r < 4; ++r) {
        float v = rs[r];
        #pragma unroll
        for (int off = 1; off < 16; off <<= 1) v += __shfl_xor(v, off, 64);
        l_i[mt][r] = l_i[mt][r] * alpha[r] + v;
      }
      #pragma unroll
      for (int nt = 0; nt < 4; ++nt)
        #pragma unroll
        for (int r = 0; r < 4; ++r) o[mt][nt][r] *= alpha[r];
      // P -> LDS (C-layout to memory, re-read in A-layout)
      #pragma unroll
      for (int nt = 0; nt < 4; ++nt)
        #pragma unroll
        for (int r = 0; r < 4; ++r)
          Ps[wave][mt * 16 + quad * 4 + r][nt * 16 + L] = f2bf(s[mt][nt][r]);
    }
    __syncthreads();  // P visible (also keeps waves in lockstep before next staging)

    // O += P V
    bf16x8 vf[4][2];
    #pragma unroll
    for (int nt = 0; nt < 4; ++nt) {
      vf[nt][0] = *reinterpret_cast<const bf16x8*>(&Vt[nt * 16 + L][quad * 8]);
      vf[nt][1] = *reinterpret_cast<const bf16x8*>(&Vt[nt * 16 + L][32 + quad * 8]);
    }
    #pragma unroll
    for (int mt = 0; mt < 2; ++mt) {
      bf16x8 pf0 = *reinterpret_cast<const bf16x8*>(&Ps[wave][mt * 16 + L][quad * 8]);
      bf16x8 pf1 = *reinterpret_cast<const bf16x8*>(&Ps[wave][mt * 16 + L][32 + quad * 8]);
      #pragma unroll
      for (int nt = 0; nt < 4; ++nt) {
        o[mt][nt] = __builtin_amdgcn_mfma_f32_16x16x32_bf16(pf0, vf[nt][0], o[mt][nt], 0, 0, 0);
        o[mt][nt] = __builtin_amdgcn_mfma_f32_16x16x32_bf16(pf1, vf[nt][1], o[mt][nt], 0, 0, 0);
      }
    }
  }

  // epilogue: y[b][t][h*64+d] bf16
  const int b = bh >> 4, h = bh & 15;
  #pragma unroll
  for (int mt = 0; mt < 2; ++mt)
    #pragma unroll
    for (int nt = 0; nt < 4; ++nt)
      #pragma unroll
      for (int r = 0; r < 4; ++r) {
        int row = qrow0 + mt * 16 + quad * 4 + r;
        float inv = 1.0f / l_i[mt][r];
        y[((size_t)b * 2048 + row) * 1024 + h * 64 + nt * 16 + L] = f2bf(o[mt][nt][r] * inv);
      }
}

extern "C" void kernel_launch(void* const* d_in, const int* in_sizes, int n_in,
                              void* d_out, int out_size, void* d_ws, size_t ws_size,
                              hipStream_t stream) {
  const float* x      = (const float*)d_in[0];  // [2,2048,1024]
  const float* w_attn = (const float*)d_in[1];  // [1024,3072]
  const float* b_attn = (const float*)d_in[2];  // [3072]
  const float* w_proj = (const float*)d_in[3];  // [1024,1024]
  const float* b_proj = (const float*)d_in[4];  // [1024]
  float* out = (float*)d_out;                   // [2,2048,1024] fp32

  unsigned short* ws = (unsigned short*)d_ws;
  unsigned short* xb     = ws;                    // 4194304
  unsigned short* wattnT = xb + 4194304;          // 3145728  [3072,1024]
  unsigned short* wprojT = wattnT + 3145728;      // 1048576  [1024,1024]
  unsigned short* qkv    = wprojT + 1048576;      // 12582912 [3][32][2048][64]
  unsigned short* yb     = qkv + 12582912;        // 4194304  [4096,1024]

  cast_bf16_kernel<<<4096, 256, 0, stream>>>(x, xb, 1048576);
  transpose_cast_kernel<<<dim3(96, 32), dim3(32, 8), 0, stream>>>(w_attn, wattnT, 1024, 3072);
  transpose_cast_kernel<<<dim3(32, 32), dim3(32, 8), 0, stream>>>(w_proj, wprojT, 1024, 1024);

  // QKV: M=4096, N=3072, K=1024
  gemm_bt_kernel<<<dim3(24, 32), 256, 0, stream>>>(xb, wattnT, b_attn, qkv, 4096, 3072, 1024, 1);
  // attention
  attn_kernel<<<dim3(16, 32), 256, 0, stream>>>(qkv, yb);
  // proj: M=4096, N=1024, K=1024
  gemm_bt_kernel<<<dim3(8, 32), 256, 0, stream>>>(yb, wprojT, b_proj, out, 4096, 1024, 1024, 0);
}

// Round 3
// 219.230 us; speedup vs baseline: 1.3073x; 1.3073x over previous
//
#include <hip/hip_runtime.h>
#include <stdint.h>

// B=2, T=2048, C=1024, H=16, HD=64
// qkv ws layout: [3][B*H=32][T=2048][HD=64] bf16 ; vt: [32][64][2048] bf16

typedef short bf16x8 __attribute__((ext_vector_type(8)));
typedef float f32x4 __attribute__((ext_vector_type(4)));

__device__ inline unsigned short f2bf(float f) {
  union { float f; uint32_t u; } v; v.f = f;
  uint32_t u = v.u;
  u += 0x7FFFu + ((u >> 16) & 1u);   // round-to-nearest-even
  return (unsigned short)(u >> 16);
}

// async global->LDS, 16B per lane, dest = lds base + lane*16
__device__ inline void load_lds16(const unsigned short* g, unsigned short* l) {
  __builtin_amdgcn_global_load_lds(
      (const __attribute__((address_space(1))) unsigned int*)(const void*)g,
      (__attribute__((address_space(3))) unsigned int*)(void*)l, 16, 0, 0);
}

// ---------- cast fp32 -> bf16 (vectorized x4) ----------
__global__ __launch_bounds__(256) void cast_bf16_kernel(
    const float* __restrict__ in, unsigned short* __restrict__ out, int n4) {
  int i = blockIdx.x * 256 + threadIdx.x;
  if (i >= n4) return;
  float4 f = reinterpret_cast<const float4*>(in)[i];
  ushort4 o;
  o.x = f2bf(f.x); o.y = f2bf(f.y); o.z = f2bf(f.z); o.w = f2bf(f.w);
  reinterpret_cast<ushort4*>(out)[i] = o;
}

// ---------- transpose [R,Cn] fp32 -> [Cn,R] bf16 ----------
__global__ void transpose_cast_kernel(
    const float* __restrict__ in, unsigned short* __restrict__ out, int R, int Cn) {
  __shared__ float tile[32][33];
  int bx = blockIdx.x * 32, by = blockIdx.y * 32;
  int tx = threadIdx.x, ty = threadIdx.y;  // block (32,8)
  #pragma unroll
  for (int i = 0; i < 32; i += 8)
    tile[ty + i][tx] = in[(size_t)(by + ty + i) * Cn + bx + tx];
  __syncthreads();
  #pragma unroll
  for (int i = 0; i < 32; i += 8)
    out[(size_t)(bx + ty + i) * R + by + tx] = f2bf(tile[tx][ty + i]);
}

// ---------- transpose V per (bh, 64-key tile): [T][64] -> [64][T] bf16 ----------
__global__ __launch_bounds__(256) void vtrans_kernel(
    const unsigned short* __restrict__ qkv, unsigned short* __restrict__ vt) {
  __shared__ unsigned short Ts[64][72];
  const int bh = blockIdx.y, kt = blockIdx.x;
  const unsigned short* vb = qkv + ((size_t)(64 + bh) * 2048) * 64;
  const int t = threadIdx.x;
  const int key = t >> 2, c0 = (t & 3) * 2;
  #pragma unroll
  for (int j = 0; j < 2; ++j) {
    uint4 u = *reinterpret_cast<const uint4*>(vb + (size_t)(kt * 64 + key) * 64 + (c0 + j) * 8);
    *reinterpret_cast<uint4*>(&Ts[key][(c0 + j) * 8]) = u;
  }
  __syncthreads();
  const int d = t >> 2;
  #pragma unroll
  for (int j = 0; j < 2; ++j) {
    int kc = c0 + j;
    ushort4 a, b;
    unsigned short* pa = reinterpret_cast<unsigned short*>(&a);
    unsigned short* pb = reinterpret_cast<unsigned short*>(&b);
    #pragma unroll
    for (int kk = 0; kk < 4; ++kk) pa[kk] = Ts[kc * 8 + kk][d];
    #pragma unroll
    for (int kk = 0; kk < 4; ++kk) pb[kk] = Ts[kc * 8 + 4 + kk][d];
    unsigned short* dst = vt + ((size_t)bh * 64 + d) * 2048 + kt * 64 + kc * 8;
    *reinterpret_cast<ushort4*>(dst) = a;
    *reinterpret_cast<ushort4*>(dst + 4) = b;
  }
}

// ---------- bf16 MFMA GEMM (m97 style): C[M,N] = A[M,K] * Bt[N,K]^T + bias ----------
// LDS unpadded 128x32 shorts, 4 chunks/row, chunk' = chunk ^ (row&3) swizzle,
// staged with global_load_lds dwordx4.
// mode 0: write fp32 to out [M,N]
// mode 1: QKV scatter: col -> (sel,h,d), row -> (b,t); q scaled by 0.125*log2e; bf16 out
__global__ __launch_bounds__(256) void gemm_bt_kernel(
    const unsigned short* __restrict__ A,
    const unsigned short* __restrict__ Bt,
    const float* __restrict__ bias,
    void* __restrict__ outp,
    int M, int N, int K, int mode) {
  __shared__ unsigned short As[128 * 32];
  __shared__ unsigned short Bs[128 * 32];
  const int t = threadIdx.x;
  const int wave = t >> 6, lane = t & 63;
  const int L = lane & 15, quad = lane >> 4;
  const int wm = (wave >> 1) * 64, wn = (wave & 1) * 64;
  const int m0 = blockIdx.y * 128, n0 = blockIdx.x * 128;

  // DMA per-lane source mapping: 16 rows per instr, lane>>2 = row, lane&3 = stored pos
  const int drow = lane >> 2;
  const int dch  = (lane & 3) ^ (drow & 3);
  // frag read swizzle: chunk quad stored at quad ^ (L&3)
  const int foff = ((quad ^ (L & 3)) * 8);

  f32x4 acc[4][4] = {};

  for (int k0 = 0; k0 < K; k0 += 32) {
    __syncthreads();
    #pragma unroll
    for (int j = 0; j < 2; ++j) {
      int r0 = wave * 32 + j * 16;
      load_lds16(A  + (size_t)(m0 + r0 + drow) * K + k0 + dch * 8, &As[r0 * 32]);
      load_lds16(Bt + (size_t)(n0 + r0 + drow) * K + k0 + dch * 8, &Bs[r0 * 32]);
    }
    __syncthreads();
    bf16x8 af[4], bf[4];
    #pragma unroll
    for (int mt = 0; mt < 4; ++mt)
      af[mt] = *reinterpret_cast<const bf16x8*>(&As[(wm + mt * 16 + L) * 32 + foff]);
    #pragma unroll
    for (int nt = 0; nt < 4; ++nt)
      bf[nt] = *reinterpret_cast<const bf16x8*>(&Bs[(wn + nt * 16 + L) * 32 + foff]);
    #pragma unroll
    for (int mt = 0; mt < 4; ++mt)
      #pragma unroll
      for (int nt = 0; nt < 4; ++nt)
        acc[mt][nt] = __builtin_amdgcn_mfma_f32_16x16x32_bf16(af[mt], bf[nt], acc[mt][nt], 0, 0, 0);
  }

  if (mode == 0) {
    float* out = (float*)outp;
    #pragma unroll
    for (int mt = 0; mt < 4; ++mt)
      #pragma unroll
      for (int nt = 0; nt < 4; ++nt) {
        int col = n0 + wn + nt * 16 + L;
        float b = bias[col];
        #pragma unroll
        for (int r = 0; r < 4; ++r) {
          int row = m0 + wm + mt * 16 + quad * 4 + r;
          out[(size_t)row * N + col] = acc[mt][nt][r] + b;
        }
      }
  } else {
    unsigned short* qkv = (unsigned short*)outp;  // [3][32][2048][64]
    #pragma unroll
    for (int mt = 0; mt < 4; ++mt)
      #pragma unroll
      for (int nt = 0; nt < 4; ++nt) {
        int col = n0 + wn + nt * 16 + L;          // 0..3071
        int sel = col >> 10, cc = col & 1023;
        int h = cc >> 6, d = cc & 63;
        float b = bias[col];
        // fold 1/sqrt(64) * log2(e) into q so attention uses exp2 directly
        float sc = (sel == 0) ? 0.18033688011112042f : 1.0f;
        #pragma unroll
        for (int r = 0; r < 4; ++r) {
          int row = m0 + wm + mt * 16 + quad * 4 + r;  // 0..4095
          int bb = row >> 11, tt = row & 2047;
          float val = (acc[mt][nt][r] + b) * sc;
          qkv[(((size_t)sel * 32 + (size_t)(bb * 16 + h)) * 2048 + tt) * 64 + d] = f2bf(val);
        }
      }
  }
}

// ---------- flash attention v2 ----------
// Fold balance: block = pair (q-tile i, q-tile 31-i), each 64 rows; 4 waves x 16 rows/side.
// No-max softmax (scores pre-scaled small; exp2 with scale folded into q).
// K and V^T staged via global_load_lds with 8-chunk XOR swizzle; P per-wave (no barrier).
__global__ __launch_bounds__(256) void attn_kernel(
    const unsigned short* __restrict__ qkv,
    const unsigned short* __restrict__ vt,
    unsigned short* __restrict__ y) {
  __shared__ unsigned short Ks[64 * 64];     // [key][d], swizzled chunks
  __shared__ unsigned short Vs[64 * 64];     // [d][key], swizzled chunks
  __shared__ unsigned short Ps[4][32][68];   // per-wave P: rows 0-15 = side A, 16-31 = side B

  const int t = threadIdx.x;
  const int wave = t >> 6, lane = t & 63;
  const int L = lane & 15, quad = lane >> 4;
  const int bh = blockIdx.y;
  const int i  = blockIdx.x;            // pair index 0..15
  const int tA = i, tB = 31 - i;        // 64-row q-tile indices
  const int rowA0 = tA * 64 + wave * 16;
  const int rowB0 = tB * 64 + wave * 16;
  const int ntiles = tB + 1;            // k-tiles 0..tB (superset of A's range)

  const unsigned short* qb  = qkv + ((size_t)bh * 2048) * 64;
  const unsigned short* kb  = qkv + ((size_t)(32 + bh) * 2048) * 64;
  const unsigned short* vtb = vt + (size_t)bh * 64 * 2048;

  // DMA per-lane constants: 8 rows (128B each) per instruction
  const int drow = lane >> 3;           // 0..7
  const int dch  = (lane & 7) ^ drow;   // source chunk (xor swizzle)
  // frag-read swizzle offsets (shorts within 128B row): chunk c stored at c^(L&7)
  const int fo[2] = { ((quad ^ (L & 7)) * 8), (((quad + 4) ^ (L & 7)) * 8) };

  // Q fragments (A-layout, direct from global, resident all kernel)
  bf16x8 qfA[2], qfB[2];
  #pragma unroll
  for (int h = 0; h < 2; ++h) {
    qfA[h] = *reinterpret_cast<const bf16x8*>(qb + (size_t)(rowA0 + L) * 64 + h * 32 + quad * 8);
    qfB[h] = *reinterpret_cast<const bf16x8*>(qb + (size_t)(rowB0 + L) * 64 + h * 32 + quad * 8);
  }

  f32x4 oA[4] = {}, oB[4] = {};
  float rsA[4] = {}, rsB[4] = {};

  for (int kt = 0; kt < ntiles; ++kt) {
    __syncthreads();
    {
      const int kg = kt * 64;
      #pragma unroll
      for (int j = 0; j < 2; ++j) {
        int r0 = wave * 16 + j * 8;
        load_lds16(kb  + (size_t)(kg + r0 + drow) * 64 + dch * 8, &Ks[r0 * 64]);
        load_lds16(vtb + (size_t)(r0 + drow) * 2048 + kg + dch * 8, &Vs[r0 * 64]);
      }
    }
    __syncthreads();

    const bool actA = (kt <= tA);

    // ---- S = Q K^T ----
    bf16x8 kf[4][2];
    #pragma unroll
    for (int nt = 0; nt < 4; ++nt)
      #pragma unroll
      for (int h = 0; h < 2; ++h)
        kf[nt][h] = *reinterpret_cast<const bf16x8*>(&Ks[(nt * 16 + L) * 64 + fo[h]]);

    f32x4 sB[4] = {};
    #pragma unroll
    for (int nt = 0; nt < 4; ++nt)
      #pragma unroll
      for (int h = 0; h < 2; ++h)
        sB[nt] = __builtin_amdgcn_mfma_f32_16x16x32_bf16(qfB[h], kf[nt][h], sB[nt], 0, 0, 0);

    if (kt == tB) {  // diagonal mask for B
      #pragma unroll
      for (int nt = 0; nt < 4; ++nt) {
        int key = kt * 64 + nt * 16 + L;
        #pragma unroll
        for (int r = 0; r < 4; ++r)
          if (key > rowB0 + quad * 4 + r) sB[nt][r] = -3.0e38f;
      }
    }
    // exp2 + P-store + l-accumulate (no reductions in loop)
    #pragma unroll
    for (int nt = 0; nt < 4; ++nt)
      #pragma unroll
      for (int r = 0; r < 4; ++r) {
        float p = exp2f(sB[nt][r]);
        rsB[r] += p;
        Ps[wave][16 + quad * 4 + r][nt * 16 + L] = f2bf(p);
      }

    if (actA) {
      f32x4 sA[4] = {};
      #pragma unroll
      for (int nt = 0; nt < 4; ++nt)
        #pragma unroll
        for (int h = 0; h < 2; ++h)
          sA[nt] = __builtin_amdgcn_mfma_f32_16x16x32_bf16(qfA[h], kf[nt][h], sA[nt], 0, 0, 0);
      if (kt == tA) {
        #pragma unroll
        for (int nt = 0; nt < 4; ++nt) {
          int key = kt * 64 + nt * 16 + L;
          #pragma unroll
          for (int r = 0; r < 4; ++r)
            if (key > rowA0 + quad * 4 + r) sA[nt][r] = -3.0e38f;
        }
      }
      #pragma unroll
      for (int nt = 0; nt < 4; ++nt)
        #pragma unroll
        for (int r = 0; r < 4; ++r) {
          float p = exp2f(sA[nt][r]);
          rsA[r] += p;
          Ps[wave][quad * 4 + r][nt * 16 + L] = f2bf(p);
        }
    }

    // ---- O += P V ----  (P round-trips per-wave LDS: C-layout -> A-layout)
    bf16x8 vf[4][2];
    #pragma unroll
    for (int nt = 0; nt < 4; ++nt)
      #pragma unroll
      for (int h = 0; h < 2; ++h)
        vf[nt][h] = *reinterpret_cast<const bf16x8*>(&Vs[(nt * 16 + L) * 64 + fo[h]]);

    bf16x8 pb0 = *reinterpret_cast<const bf16x8*>(&Ps[wave][16 + L][quad * 8]);
    bf16x8 pb1 = *reinterpret_cast<const bf16x8*>(&Ps[wave][16 + L][32 + quad * 8]);
    #pragma unroll
    for (int nt = 0; nt < 4; ++nt) {
      oB[nt] = __builtin_amdgcn_mfma_f32_16x16x32_bf16(pb0, vf[nt][0], oB[nt], 0, 0, 0);
      oB[nt] = __builtin_amdgcn_mfma_f32_16x16x32_bf16(pb1, vf[nt][1], oB[nt], 0, 0, 0);
    }
    if (actA) {
      bf16x8 pa0 = *reinterpret_cast<const bf16x8*>(&Ps[wave][L][quad * 8]);
      bf16x8 pa1 = *reinterpret_cast<const bf16x8*>(&Ps[wave][L][32 + quad * 8]);
      #pragma unroll
      for (int nt = 0; nt < 4; ++nt) {
        oA[nt] = __builtin_amdgcn_mfma_f32_16x16x32_bf16(pa0, vf[nt][0], oA[nt], 0, 0, 0);
        oA[nt] = __builtin_amdgcn_mfma_f32_16x16x32_bf16(pa1, vf[nt][1], oA[nt], 0, 0, 0);
      }
    }
  }

  // ---- epilogue: single l-reduction, then y writes ----
  float invA[4], invB[4];
  #pragma unroll
  for (int r = 0; r < 4; ++r) {
    float a = rsA[r], b = rsB[r];
    #pragma unroll
    for (int off = 1; off < 16; off <<= 1) {
      a += __shfl_xor(a, off, 64);
      b += __shfl_xor(b, off, 64);
    }
    invA[r] = 1.0f / a;
    invB[r] = 1.0f / b;
  }
  const int bb = bh >> 4, hh = bh & 15;
  #pragma unroll
  for (int nt = 0; nt < 4; ++nt)
    #pragma unroll
    for (int r = 0; r < 4; ++r) {
      int rA = rowA0 + quad * 4 + r;
      int rB = rowB0 + quad * 4 + r;
      int col = hh * 64 + nt * 16 + L;
      y[((size_t)bb * 2048 + rA) * 1024 + col] = f2bf(oA[nt][r] * invA[r]);
      y[((size_t)bb * 2048 + rB) * 1024 + col] = f2bf(oB[nt][r] * invB[r]);
    }
}

extern "C" void kernel_launch(void* const* d_in, const int* in_sizes, int n_in,
                              void* d_out, int out_size, void* d_ws, size_t ws_size,
                              hipStream_t stream) {
  const float* x      = (const float*)d_in[0];  // [2,2048,1024]
  const float* w_attn = (const float*)d_in[1];  // [1024,3072]
  const float* b_attn = (const float*)d_in[2];  // [3072]
  const float* w_proj = (const float*)d_in[3];  // [1024,1024]
  const float* b_proj = (const float*)d_in[4];  // [1024]
  float* out = (float*)d_out;                   // [2,2048,1024] fp32

  unsigned short* ws = (unsigned short*)d_ws;
  unsigned short* xb     = ws;                    //  4194304 [4096,1024]
  unsigned short* wattnT = xb + 4194304;          //  3145728 [3072,1024]
  unsigned short* wprojT = wattnT + 3145728;      //  1048576 [1024,1024]
  unsigned short* qkv    = wprojT + 1048576;      // 12582912 [3][32][2048][64]
  unsigned short* yb     = qkv + 12582912;        //  4194304 [4096,1024]
  unsigned short* vt     = yb + 4194304;          //  4194304 [32][64][2048]

  cast_bf16_kernel<<<4096, 256, 0, stream>>>(x, xb, 1048576);
  transpose_cast_kernel<<<dim3(96, 32), dim3(32, 8), 0, stream>>>(w_attn, wattnT, 1024, 3072);
  transpose_cast_kernel<<<dim3(32, 32), dim3(32, 8), 0, stream>>>(w_proj, wprojT, 1024, 1024);

  // QKV: M=4096, N=3072, K=1024
  gemm_bt_kernel<<<dim3(24, 32), 256, 0, stream>>>(xb, wattnT, b_attn, qkv, 4096, 3072, 1024, 1);
  // V transpose per (bh, key-tile)
  vtrans_kernel<<<dim3(32, 32), 256, 0, stream>>>(qkv, vt);
  // attention (fold-balanced)
  attn_kernel<<<dim3(16, 32), 256, 0, stream>>>(qkv, vt, yb);
  // proj: M=4096, N=1024, K=1024
  gemm_bt_kernel<<<dim3(8, 32), 256, 0, stream>>>(yb, wprojT, b_proj, out, 4096, 1024, 1024, 0);
}

// Round 4
// 205.858 us; speedup vs baseline: 1.3923x; 1.0650x over previous
//
#include <hip/hip_runtime.h>
#include <stdint.h>

// B=2, T=2048, C=1024, H=16, HD=64
// qkv ws layout: [3][B*H=32][T=2048][HD=64] bf16 (v region unused); vt: [32][64][2048] bf16

typedef short bf16x8 __attribute__((ext_vector_type(8)));
typedef float f32x4 __attribute__((ext_vector_type(4)));

__device__ inline unsigned short f2bf(float f) {
  union { float f; uint32_t u; } v; v.f = f;
  uint32_t u = v.u;
  u += 0x7FFFu + ((u >> 16) & 1u);   // round-to-nearest-even
  return (unsigned short)(u >> 16);
}

// pack two fp32 -> two bf16 in one dword (RNE)
__device__ inline unsigned pkbf(float a, float b) {
#if __has_builtin(__builtin_amdgcn_cvt_pk_bf16_f32)
  typedef __bf16 v2bf __attribute__((ext_vector_type(2)));
  v2bf v = __builtin_amdgcn_cvt_pk_bf16_f32(a, b);
  unsigned u; __builtin_memcpy(&u, &v, 4); return u;
#else
  return (unsigned)f2bf(a) | ((unsigned)f2bf(b) << 16);
#endif
}

// async global->LDS, 16B per lane, dest = lds base + lane*16
__device__ inline void load_lds16(const unsigned short* g, unsigned short* l) {
  __builtin_amdgcn_global_load_lds(
      (const __attribute__((address_space(1))) unsigned int*)(const void*)g,
      (__attribute__((address_space(3))) unsigned int*)(void*)l, 16, 0, 0);
}

// ---------- cast fp32 -> bf16 (vectorized x4) ----------
__global__ __launch_bounds__(256) void cast_bf16_kernel(
    const float* __restrict__ in, unsigned short* __restrict__ out, int n4) {
  int i = blockIdx.x * 256 + threadIdx.x;
  if (i >= n4) return;
  float4 f = reinterpret_cast<const float4*>(in)[i];
  ushort4 o;
  o.x = f2bf(f.x); o.y = f2bf(f.y); o.z = f2bf(f.z); o.w = f2bf(f.w);
  reinterpret_cast<ushort4*>(out)[i] = o;
}

// ---------- transpose [R,Cn] fp32 -> [Cn,R] bf16 ----------
__global__ void transpose_cast_kernel(
    const float* __restrict__ in, unsigned short* __restrict__ out, int R, int Cn) {
  __shared__ float tile[32][33];
  int bx = blockIdx.x * 32, by = blockIdx.y * 32;
  int tx = threadIdx.x, ty = threadIdx.y;  // block (32,8)
  #pragma unroll
  for (int i = 0; i < 32; i += 8)
    tile[ty + i][tx] = in[(size_t)(by + ty + i) * Cn + bx + tx];
  __syncthreads();
  #pragma unroll
  for (int i = 0; i < 32; i += 8)
    out[(size_t)(bx + ty + i) * R + by + tx] = f2bf(tile[tx][ty + i]);
}

// ---------- bf16 MFMA GEMM: C[M,N] = A[M,K] * Bt[N,K]^T + bias ----------
// LDS unpadded 128x32 shorts; chunk swizzle pos = c ^ ((row>>1)&3) (conflict-free
// b128 frag reads: row parity supplies the 5th bank bit). Staged with
// global_load_lds dwordx4.
// mode 0: write fp32 to out [M,N]
// mode 1: QKV scatter: q/k -> qkv layout (q scaled by 0.125*log2e), v -> vt[bh][d][t]
__global__ __launch_bounds__(256) void gemm_bt_kernel(
    const unsigned short* __restrict__ A,
    const unsigned short* __restrict__ Bt,
    const float* __restrict__ bias,
    void* __restrict__ outp,
    unsigned short* __restrict__ vtp,
    int M, int N, int K, int mode) {
  __shared__ unsigned short As[128 * 32];
  __shared__ unsigned short Bs[128 * 32];
  const int t = threadIdx.x;
  const int wave = t >> 6, lane = t & 63;
  const int L = lane & 15, quad = lane >> 4;
  const int wm = (wave >> 1) * 64, wn = (wave & 1) * 64;
  const int m0 = blockIdx.y * 128, n0 = blockIdx.x * 128;

  // DMA per-lane source mapping: 16 rows per instr, lane>>2 = row, lane&3 = stored pos
  const int drow = lane >> 2;
  const int dch  = (lane & 3) ^ ((drow >> 1) & 3);
  // frag read: logical chunk `quad` of row L stored at quad ^ ((L>>1)&3)
  const int foff = ((quad ^ ((L >> 1) & 3)) * 8);

  f32x4 acc[4][4] = {};

  for (int k0 = 0; k0 < K; k0 += 32) {
    __syncthreads();
    #pragma unroll
    for (int j = 0; j < 2; ++j) {
      int r0 = wave * 32 + j * 16;
      load_lds16(A  + (size_t)(m0 + r0 + drow) * K + k0 + dch * 8, &As[r0 * 32]);
      load_lds16(Bt + (size_t)(n0 + r0 + drow) * K + k0 + dch * 8, &Bs[r0 * 32]);
    }
    __syncthreads();
    bf16x8 af[4], bf[4];
    #pragma unroll
    for (int mt = 0; mt < 4; ++mt)
      af[mt] = *reinterpret_cast<const bf16x8*>(&As[(wm + mt * 16 + L) * 32 + foff]);
    #pragma unroll
    for (int nt = 0; nt < 4; ++nt)
      bf[nt] = *reinterpret_cast<const bf16x8*>(&Bs[(wn + nt * 16 + L) * 32 + foff]);
    #pragma unroll
    for (int mt = 0; mt < 4; ++mt)
      #pragma unroll
      for (int nt = 0; nt < 4; ++nt)
        acc[mt][nt] = __builtin_amdgcn_mfma_f32_16x16x32_bf16(af[mt], bf[nt], acc[mt][nt], 0, 0, 0);
  }

  if (mode == 0) {
    float* out = (float*)outp;
    #pragma unroll
    for (int mt = 0; mt < 4; ++mt)
      #pragma unroll
      for (int nt = 0; nt < 4; ++nt) {
        int col = n0 + wn + nt * 16 + L;
        float b = bias[col];
        #pragma unroll
        for (int r = 0; r < 4; ++r) {
          int row = m0 + wm + mt * 16 + quad * 4 + r;
          out[(size_t)row * N + col] = acc[mt][nt][r] + b;
        }
      }
  } else {
    unsigned short* qkv = (unsigned short*)outp;  // [3][32][2048][64]
    #pragma unroll
    for (int mt = 0; mt < 4; ++mt)
      #pragma unroll
      for (int nt = 0; nt < 4; ++nt) {
        int col = n0 + wn + nt * 16 + L;          // 0..3071
        int sel = col >> 10, cc = col & 1023;
        int h = cc >> 6, d = cc & 63;
        float b = bias[col];
        // fold 1/sqrt(64) * log2(e) into q so attention uses exp2 directly
        float sc = (sel == 0) ? 0.18033688011112042f : 1.0f;
        #pragma unroll
        for (int r = 0; r < 4; ++r) {
          int row = m0 + wm + mt * 16 + quad * 4 + r;  // 0..4095
          int bb = row >> 11, tt = row & 2047;
          float val = (acc[mt][nt][r] + b) * sc;
          if (sel == 2) {
            // v -> vt[bh][d][t]  (fused V transpose)
            vtp[((size_t)(bb * 16 + h) * 64 + d) * 2048 + tt] = f2bf(val);
          } else {
            qkv[(((size_t)sel * 32 + (size_t)(bb * 16 + h)) * 2048 + tt) * 64 + d] = f2bf(val);
          }
        }
      }
  }
}

// ---------- flash attention v3 ----------
// Pair fold-balance: block = (q-tile i, q-tile 31-i), 64 rows each; 4 waves x (16A+16B rows).
// S^T via swapped MFMA operands -> key on register axis -> packed ds_write_b64 P-store,
// scalar l-accumulator. 3-buffer K/V pipeline: stage(kt+1); vmcnt(4); s_barrier; compute(kt).
__global__ __launch_bounds__(256) void attn_kernel(
    const unsigned short* __restrict__ qkv,
    const unsigned short* __restrict__ vt,
    unsigned short* __restrict__ y) {
  __shared__ unsigned short Ks[3][64 * 64];  // [key][d], swizzled chunks
  __shared__ unsigned short Vs[3][64 * 64];  // [d][key], swizzled chunks
  __shared__ unsigned short Ps[4][32][72];   // per-wave P[qrow][key]: rows 0-15 A, 16-31 B

  const int t = threadIdx.x;
  const int wave = t >> 6, lane = t & 63;
  const int L = lane & 15, quad = lane >> 4;
  const int bh = blockIdx.y;
  const int pi = blockIdx.x;            // pair index 0..15
  const int tA = pi, tB = 31 - pi;      // 64-row q-tile indices
  const int rowA0 = tA * 64 + wave * 16;
  const int rowB0 = tB * 64 + wave * 16;
  const int ntiles = tB + 1;

  const unsigned short* qb  = qkv + ((size_t)bh * 2048) * 64;
  const unsigned short* kb  = qkv + ((size_t)(32 + bh) * 2048) * 64;
  const unsigned short* vtb = vt + (size_t)bh * 64 * 2048;

  // DMA per-lane constants: 8 rows (128B each) per instruction
  const int drow = lane >> 3;           // 0..7
  const int dch  = (lane & 7) ^ drow;   // source chunk (xor swizzle)
  // frag-read swizzle offsets: chunk c of row r stored at c^(r&7)
  const int fo0 = ((quad ^ (L & 7)) * 8);
  const int fo1 = (((quad + 4) ^ (L & 7)) * 8);

  // Q fragments (16x16x32 A/B-operand layout, direct from global, resident all kernel)
  bf16x8 qfA[2], qfB[2];
  #pragma unroll
  for (int h = 0; h < 2; ++h) {
    qfA[h] = *reinterpret_cast<const bf16x8*>(qb + (size_t)(rowA0 + L) * 64 + h * 32 + quad * 8);
    qfB[h] = *reinterpret_cast<const bf16x8*>(qb + (size_t)(rowB0 + L) * 64 + h * 32 + quad * 8);
  }

  f32x4 oA[4] = {}, oB[4] = {};
  float rsA = 0.f, rsB = 0.f;

  // prologue: stage tile 0 -> buf 0 (4 DMA instrs per wave per stage)
  {
    #pragma unroll
    for (int j = 0; j < 2; ++j) {
      int r0 = wave * 16 + j * 8;
      load_lds16(kb  + (size_t)(0 + r0 + drow) * 64 + dch * 8, &Ks[0][r0 * 64]);
      load_lds16(vtb + (size_t)(r0 + drow) * 2048 + 0 + dch * 8, &Vs[0][r0 * 64]);
    }
  }

  int buf = 0;
  for (int kt = 0; kt < ntiles; ++kt) {
    // stage kt+1 (clamped dummy on last iter keeps vmcnt accounting uniform)
    const int nkt = (kt + 1 < ntiles) ? kt + 1 : ntiles - 1;
    const int nbuf = (buf == 2) ? 0 : buf + 1;
    {
      const int kg = nkt * 64;
      #pragma unroll
      for (int j = 0; j < 2; ++j) {
        int r0 = wave * 16 + j * 8;
        load_lds16(kb  + (size_t)(kg + r0 + drow) * 64 + dch * 8, &Ks[nbuf][r0 * 64]);
        load_lds16(vtb + (size_t)(r0 + drow) * 2048 + kg + dch * 8, &Vs[nbuf][r0 * 64]);
      }
    }
    asm volatile("" ::: "memory");
    __builtin_amdgcn_s_waitcnt(0x0F74);   // vmcnt(4): tile kt's 4 DMAs done; kt+1 in flight
    __builtin_amdgcn_s_barrier();
    asm volatile("" ::: "memory");

    const bool actA = (kt <= tA);

    // ---- S^T = K Q^T : D[m=key][n=qrow] (A=K-frag, B=Q-frag) ----
    bf16x8 kf[4][2];
    #pragma unroll
    for (int nt = 0; nt < 4; ++nt) {
      kf[nt][0] = *reinterpret_cast<const bf16x8*>(&Ks[buf][(nt * 16 + L) * 64 + fo0]);
      kf[nt][1] = *reinterpret_cast<const bf16x8*>(&Ks[buf][(nt * 16 + L) * 64 + fo1]);
    }

    f32x4 sB[4] = {};
    #pragma unroll
    for (int nt = 0; nt < 4; ++nt) {
      sB[nt] = __builtin_amdgcn_mfma_f32_16x16x32_bf16(kf[nt][0], qfB[0], sB[nt], 0, 0, 0);
      sB[nt] = __builtin_amdgcn_mfma_f32_16x16x32_bf16(kf[nt][1], qfB[1], sB[nt], 0, 0, 0);
    }
    if (kt == tB) {  // diagonal mask: key > qrow -> -inf
      #pragma unroll
      for (int nt = 0; nt < 4; ++nt) {
        int key0 = kt * 64 + nt * 16 + quad * 4;
        int qr = rowB0 + L;
        #pragma unroll
        for (int r = 0; r < 4; ++r)
          if (key0 + r > qr) sB[nt][r] = -3.0e38f;
      }
    }
    #pragma unroll
    for (int nt = 0; nt < 4; ++nt) {
      float p0 = exp2f(sB[nt][0]), p1 = exp2f(sB[nt][1]);
      float p2 = exp2f(sB[nt][2]), p3 = exp2f(sB[nt][3]);
      rsB += (p0 + p1) + (p2 + p3);
      uint2 pk;
      pk.x = pkbf(p0, p1);
      pk.y = pkbf(p2, p3);
      *reinterpret_cast<uint2*>(&Ps[wave][16 + L][nt * 16 + quad * 4]) = pk;
    }

    if (actA) {
      f32x4 sA[4] = {};
      #pragma unroll
      for (int nt = 0; nt < 4; ++nt) {
        sA[nt] = __builtin_amdgcn_mfma_f32_16x16x32_bf16(kf[nt][0], qfA[0], sA[nt], 0, 0, 0);
        sA[nt] = __builtin_amdgcn_mfma_f32_16x16x32_bf16(kf[nt][1], qfA[1], sA[nt], 0, 0, 0);
      }
      if (kt == tA) {
        #pragma unroll
        for (int nt = 0; nt < 4; ++nt) {
          int key0 = kt * 64 + nt * 16 + quad * 4;
          int qr = rowA0 + L;
          #pragma unroll
          for (int r = 0; r < 4; ++r)
            if (key0 + r > qr) sA[nt][r] = -3.0e38f;
        }
      }
      #pragma unroll
      for (int nt = 0; nt < 4; ++nt) {
        float p0 = exp2f(sA[nt][0]), p1 = exp2f(sA[nt][1]);
        float p2 = exp2f(sA[nt][2]), p3 = exp2f(sA[nt][3]);
        rsA += (p0 + p1) + (p2 + p3);
        uint2 pk;
        pk.x = pkbf(p0, p1);
        pk.y = pkbf(p2, p3);
        *reinterpret_cast<uint2*>(&Ps[wave][L][nt * 16 + quad * 4]) = pk;
      }
    }

    // ---- O += P V ----  (P in A-layout directly from Ps[qrow][key])
    bf16x8 vf[4][2];
    #pragma unroll
    for (int nt = 0; nt < 4; ++nt) {
      vf[nt][0] = *reinterpret_cast<const bf16x8*>(&Vs[buf][(nt * 16 + L) * 64 + fo0]);
      vf[nt][1] = *reinterpret_cast<const bf16x8*>(&Vs[buf][(nt * 16 + L) * 64 + fo1]);
    }
    bf16x8 pb0 = *reinterpret_cast<const bf16x8*>(&Ps[wave][16 + L][quad * 8]);
    bf16x8 pb1 = *reinterpret_cast<const bf16x8*>(&Ps[wave][16 + L][32 + quad * 8]);
    #pragma unroll
    for (int nt = 0; nt < 4; ++nt) {
      oB[nt] = __builtin_amdgcn_mfma_f32_16x16x32_bf16(pb0, vf[nt][0], oB[nt], 0, 0, 0);
      oB[nt] = __builtin_amdgcn_mfma_f32_16x16x32_bf16(pb1, vf[nt][1], oB[nt], 0, 0, 0);
    }
    if (actA) {
      bf16x8 pa0 = *reinterpret_cast<const bf16x8*>(&Ps[wave][L][quad * 8]);
      bf16x8 pa1 = *reinterpret_cast<const bf16x8*>(&Ps[wave][L][32 + quad * 8]);
      #pragma unroll
      for (int nt = 0; nt < 4; ++nt) {
        oA[nt] = __builtin_amdgcn_mfma_f32_16x16x32_bf16(pa0, vf[nt][0], oA[nt], 0, 0, 0);
        oA[nt] = __builtin_amdgcn_mfma_f32_16x16x32_bf16(pa1, vf[nt][1], oA[nt], 0, 0, 0);
      }
    }
    buf = nbuf;
  }

  // ---- epilogue: reduce l across quads (rows live on L), fetch per-output-row via shfl ----
  float a = rsA; a += __shfl_xor(a, 16, 64); a += __shfl_xor(a, 32, 64);
  float b2 = rsB; b2 += __shfl_xor(b2, 16, 64); b2 += __shfl_xor(b2, 32, 64);
  float invA[4], invB[4];
  #pragma unroll
  for (int r = 0; r < 4; ++r) {
    invA[r] = 1.0f / __shfl(a, quad * 4 + r, 64);
    invB[r] = 1.0f / __shfl(b2, quad * 4 + r, 64);
  }
  const int bb = bh >> 4, hh = bh & 15;
  #pragma unroll
  for (int nt = 0; nt < 4; ++nt)
    #pragma unroll
    for (int r = 0; r < 4; ++r) {
      int rA = rowA0 + quad * 4 + r;
      int rB = rowB0 + quad * 4 + r;
      int col = hh * 64 + nt * 16 + L;
      y[((size_t)bb * 2048 + rA) * 1024 + col] = f2bf(oA[nt][r] * invA[r]);
      y[((size_t)bb * 2048 + rB) * 1024 + col] = f2bf(oB[nt][r] * invB[r]);
    }
  // drain outstanding dummy DMAs before LDS dealloc at wave end
  __builtin_amdgcn_s_waitcnt(0);
}

extern "C" void kernel_launch(void* const* d_in, const int* in_sizes, int n_in,
                              void* d_out, int out_size, void* d_ws, size_t ws_size,
                              hipStream_t stream) {
  const float* x      = (const float*)d_in[0];  // [2,2048,1024]
  const float* w_attn = (const float*)d_in[1];  // [1024,3072]
  const float* b_attn = (const float*)d_in[2];  // [3072]
  const float* w_proj = (const float*)d_in[3];  // [1024,1024]
  const float* b_proj = (const float*)d_in[4];  // [1024]
  float* out = (float*)d_out;                   // [2,2048,1024] fp32

  unsigned short* ws = (unsigned short*)d_ws;
  unsigned short* xb     = ws;                    //  4194304 [4096,1024]
  unsigned short* wattnT = xb + 4194304;          //  3145728 [3072,1024]
  unsigned short* wprojT = wattnT + 3145728;      //  1048576 [1024,1024]
  unsigned short* qkv    = wprojT + 1048576;      // 12582912 [3][32][2048][64] (v unused)
  unsigned short* yb     = qkv + 12582912;        //  4194304 [4096,1024]
  unsigned short* vt     = yb + 4194304;          //  4194304 [32][64][2048]

  cast_bf16_kernel<<<4096, 256, 0, stream>>>(x, xb, 1048576);
  transpose_cast_kernel<<<dim3(96, 32), dim3(32, 8), 0, stream>>>(w_attn, wattnT, 1024, 3072);
  transpose_cast_kernel<<<dim3(32, 32), dim3(32, 8), 0, stream>>>(w_proj, wprojT, 1024, 1024);

  // QKV: M=4096, N=3072, K=1024 (v transposed into vt in-epilogue)
  gemm_bt_kernel<<<dim3(24, 32), 256, 0, stream>>>(xb, wattnT, b_attn, qkv, vt, 4096, 3072, 1024, 1);
  // attention (fold-balanced, pipelined)
  attn_kernel<<<dim3(16, 32), 256, 0, stream>>>(qkv, vt, yb);
  // proj: M=4096, N=1024, K=1024
  gemm_bt_kernel<<<dim3(8, 32), 256, 0, stream>>>(yb, wprojT, b_proj, out, nullptr, 4096, 1024, 1024, 0);
}

// Round 5
// 195.525 us; speedup vs baseline: 1.4658x; 1.0528x over previous
//
#include <hip/hip_runtime.h>
#include <stdint.h>

// B=2, T=2048, C=1024, H=16, HD=64
// qkv ws layout: [3][B*H=32][T=2048][HD=64] bf16 (v region unused); vt: [32][64][2048] bf16

typedef short bf16x8 __attribute__((ext_vector_type(8)));
typedef float f32x4 __attribute__((ext_vector_type(4)));

__device__ inline unsigned short f2bf(float f) {
  union { float f; uint32_t u; } v; v.f = f;
  uint32_t u = v.u;
  u += 0x7FFFu + ((u >> 16) & 1u);   // round-to-nearest-even
  return (unsigned short)(u >> 16);
}

// pack two fp32 -> two bf16 in one dword (RNE)
__device__ inline unsigned pkbf(float a, float b) {
#if __has_builtin(__builtin_amdgcn_cvt_pk_bf16_f32)
  typedef __bf16 v2bf __attribute__((ext_vector_type(2)));
  v2bf v = __builtin_amdgcn_cvt_pk_bf16_f32(a, b);
  unsigned u; __builtin_memcpy(&u, &v, 4); return u;
#else
  return (unsigned)f2bf(a) | ((unsigned)f2bf(b) << 16);
#endif
}

// async global->LDS, 16B per lane, dest = lds base + lane*16
__device__ inline void load_lds16(const unsigned short* g, unsigned short* l) {
  __builtin_amdgcn_global_load_lds(
      (const __attribute__((address_space(1))) unsigned int*)(const void*)g,
      (__attribute__((address_space(3))) unsigned int*)(void*)l, 16, 0, 0);
}

// ---------- cast fp32 -> bf16 (vectorized x4) ----------
__global__ __launch_bounds__(256) void cast_bf16_kernel(
    const float* __restrict__ in, unsigned short* __restrict__ out, int n4) {
  int i = blockIdx.x * 256 + threadIdx.x;
  if (i >= n4) return;
  float4 f = reinterpret_cast<const float4*>(in)[i];
  ushort4 o;
  o.x = f2bf(f.x); o.y = f2bf(f.y); o.z = f2bf(f.z); o.w = f2bf(f.w);
  reinterpret_cast<ushort4*>(out)[i] = o;
}

// ---------- transpose [R,Cn] fp32 -> [Cn,R] bf16 ----------
__global__ void transpose_cast_kernel(
    const float* __restrict__ in, unsigned short* __restrict__ out, int R, int Cn) {
  __shared__ float tile[32][33];
  int bx = blockIdx.x * 32, by = blockIdx.y * 32;
  int tx = threadIdx.x, ty = threadIdx.y;  // block (32,8)
  #pragma unroll
  for (int i = 0; i < 32; i += 8)
    tile[ty + i][tx] = in[(size_t)(by + ty + i) * Cn + bx + tx];
  __syncthreads();
  #pragma unroll
  for (int i = 0; i < 32; i += 8)
    out[(size_t)(bx + ty + i) * R + by + tx] = f2bf(tile[tx][ty + i]);
}

// ---------- bf16 MFMA GEMM: C[M,N] = A[M,K] * Bt[N,K]^T + bias ----------
// 3-buffer LDS, single-barrier pipelined K-loop: stage(kt+1); vmcnt(4); s_barrier;
// compute(kt). Unpadded 128x32-short tiles, chunk swizzle pos = c ^ ((row>>1)&3).
// mode 0: write fp32 to out [M,N]
// mode 1: QKV scatter: q/k -> qkv layout (q scaled by 0.125*log2e), v -> vt[bh][d][t]
__global__ __launch_bounds__(256) void gemm_bt_kernel(
    const unsigned short* __restrict__ A,
    const unsigned short* __restrict__ Bt,
    const float* __restrict__ bias,
    void* __restrict__ outp,
    unsigned short* __restrict__ vtp,
    int M, int N, int K, int mode) {
  __shared__ unsigned short As[3][128 * 32];
  __shared__ unsigned short Bs[3][128 * 32];
  const int t = threadIdx.x;
  const int wave = t >> 6, lane = t & 63;
  const int L = lane & 15, quad = lane >> 4;
  const int wm = (wave >> 1) * 64, wn = (wave & 1) * 64;
  const int m0 = blockIdx.y * 128, n0 = blockIdx.x * 128;

  // DMA per-lane source mapping: 16 rows per instr, lane>>2 = row, lane&3 = stored pos
  const int drow = lane >> 2;
  const int dch  = (lane & 3) ^ ((drow >> 1) & 3);
  // frag read: logical chunk `quad` of row L stored at quad ^ ((L>>1)&3)
  const int foff = ((quad ^ ((L >> 1) & 3)) * 8);

  const unsigned short* Ab = A  + (size_t)(m0 + wave * 32 + drow) * K + dch * 8;
  const unsigned short* Bb = Bt + (size_t)(n0 + wave * 32 + drow) * K + dch * 8;

  f32x4 acc[4][4] = {};
  const int NK = K >> 5;

  // prologue: stage tile 0 -> buf 0
  #pragma unroll
  for (int j = 0; j < 2; ++j) {
    int r0 = wave * 32 + j * 16;
    load_lds16(Ab + (size_t)j * 16 * K, &As[0][r0 * 32]);
    load_lds16(Bb + (size_t)j * 16 * K, &Bs[0][r0 * 32]);
  }

  int buf = 0;
  for (int kt = 0; kt < NK; ++kt) {
    const int nkt = (kt + 1 < NK) ? kt + 1 : kt;  // clamped dummy keeps vmcnt uniform
    const int nbuf = (buf == 2) ? 0 : buf + 1;
    #pragma unroll
    for (int j = 0; j < 2; ++j) {
      int r0 = wave * 32 + j * 16;
      load_lds16(Ab + (size_t)j * 16 * K + nkt * 32, &As[nbuf][r0 * 32]);
      load_lds16(Bb + (size_t)j * 16 * K + nkt * 32, &Bs[nbuf][r0 * 32]);
    }
    asm volatile("" ::: "memory");
    __builtin_amdgcn_s_waitcnt(0x0F74);   // vmcnt(4): tile kt landed; kt+1 in flight
    __builtin_amdgcn_s_barrier();
    asm volatile("" ::: "memory");

    bf16x8 af[4], bf[4];
    #pragma unroll
    for (int mt = 0; mt < 4; ++mt)
      af[mt] = *reinterpret_cast<const bf16x8*>(&As[buf][(wm + mt * 16 + L) * 32 + foff]);
    #pragma unroll
    for (int nt = 0; nt < 4; ++nt)
      bf[nt] = *reinterpret_cast<const bf16x8*>(&Bs[buf][(wn + nt * 16 + L) * 32 + foff]);
    #pragma unroll
    for (int mt = 0; mt < 4; ++mt)
      #pragma unroll
      for (int nt = 0; nt < 4; ++nt)
        acc[mt][nt] = __builtin_amdgcn_mfma_f32_16x16x32_bf16(af[mt], bf[nt], acc[mt][nt], 0, 0, 0);
    buf = nbuf;
  }
  __builtin_amdgcn_s_waitcnt(0x0F70);     // drain dummy DMAs (vmcnt 0)

  if (mode == 0) {
    float* out = (float*)outp;
    #pragma unroll
    for (int mt = 0; mt < 4; ++mt)
      #pragma unroll
      for (int nt = 0; nt < 4; ++nt) {
        int col = n0 + wn + nt * 16 + L;
        float b = bias[col];
        #pragma unroll
        for (int r = 0; r < 4; ++r) {
          int row = m0 + wm + mt * 16 + quad * 4 + r;
          out[(size_t)row * N + col] = acc[mt][nt][r] + b;
        }
      }
  } else {
    unsigned short* qkv = (unsigned short*)outp;  // [3][32][2048][64]
    #pragma unroll
    for (int mt = 0; mt < 4; ++mt)
      #pragma unroll
      for (int nt = 0; nt < 4; ++nt) {
        int col = n0 + wn + nt * 16 + L;          // 0..3071
        int sel = col >> 10, cc = col & 1023;
        int h = cc >> 6, d = cc & 63;
        float b = bias[col];
        // fold 1/sqrt(64) * log2(e) into q so attention uses exp2 directly
        float sc = (sel == 0) ? 0.18033688011112042f : 1.0f;
        #pragma unroll
        for (int r = 0; r < 4; ++r) {
          int row = m0 + wm + mt * 16 + quad * 4 + r;  // 0..4095
          int bb = row >> 11, tt = row & 2047;
          float val = (acc[mt][nt][r] + b) * sc;
          if (sel == 2) {
            // v -> vt[bh][d][t]  (fused V transpose)
            vtp[((size_t)(bb * 16 + h) * 64 + d) * 2048 + tt] = f2bf(val);
          } else {
            qkv[(((size_t)sel * 32 + (size_t)(bb * 16 + h)) * 2048 + tt) * 64 + d] = f2bf(val);
          }
        }
      }
  }
}

// ---------- flash attention v4 ----------
// Pair fold-balance + XCD-aware decode: all 16 pair-blocks of a bh share one mod-8
// residue class -> same XCD L2 caches that bh's K/V (cuts HBM re-fetch ~8x).
// S^T via swapped MFMA operands; 3-buffer K/V pipeline, single barrier per tile.
__global__ __launch_bounds__(256) void attn_kernel(
    const unsigned short* __restrict__ qkv,
    const unsigned short* __restrict__ vt,
    unsigned short* __restrict__ y) {
  __shared__ unsigned short Ks[3][64 * 64];  // [key][d], swizzled chunks
  __shared__ unsigned short Vs[3][64 * 64];  // [d][key], swizzled chunks
  __shared__ unsigned short Ps[4][32][72];   // per-wave P[qrow][key]: rows 0-15 A, 16-31 B

  const int t = threadIdx.x;
  const int wave = t >> 6, lane = t & 63;
  const int L = lane & 15, quad = lane >> 4;
  // XCD-aware decode: residue class (b&7) -> XCD; 4 bh per class x 16 pairs
  const int b = blockIdx.x;
  const int bh = (b & 7) * 4 + ((b >> 3) & 3);
  const int pi = b >> 5;                // pair index 0..15
  const int tA = pi, tB = 31 - pi;      // 64-row q-tile indices
  const int rowA0 = tA * 64 + wave * 16;
  const int rowB0 = tB * 64 + wave * 16;
  const int ntiles = tB + 1;

  const unsigned short* qb  = qkv + ((size_t)bh * 2048) * 64;
  const unsigned short* kb  = qkv + ((size_t)(32 + bh) * 2048) * 64;
  const unsigned short* vtb = vt + (size_t)bh * 64 * 2048;

  // DMA per-lane constants: 8 rows (128B each) per instruction
  const int drow = lane >> 3;           // 0..7
  const int dch  = (lane & 7) ^ drow;   // source chunk (xor swizzle)
  // frag-read swizzle offsets: chunk c of row r stored at c^(r&7)
  const int fo0 = ((quad ^ (L & 7)) * 8);
  const int fo1 = (((quad + 4) ^ (L & 7)) * 8);

  // Q fragments (A/B-operand layout, direct from global, resident all kernel)
  bf16x8 qfA[2], qfB[2];
  #pragma unroll
  for (int h = 0; h < 2; ++h) {
    qfA[h] = *reinterpret_cast<const bf16x8*>(qb + (size_t)(rowA0 + L) * 64 + h * 32 + quad * 8);
    qfB[h] = *reinterpret_cast<const bf16x8*>(qb + (size_t)(rowB0 + L) * 64 + h * 32 + quad * 8);
  }

  f32x4 oA[4] = {}, oB[4] = {};
  float rsA = 0.f, rsB = 0.f;

  // prologue: stage tile 0 -> buf 0 (4 DMA instrs per wave per stage)
  {
    #pragma unroll
    for (int j = 0; j < 2; ++j) {
      int r0 = wave * 16 + j * 8;
      load_lds16(kb  + (size_t)(0 + r0 + drow) * 64 + dch * 8, &Ks[0][r0 * 64]);
      load_lds16(vtb + (size_t)(r0 + drow) * 2048 + 0 + dch * 8, &Vs[0][r0 * 64]);
    }
  }

  int buf = 0;
  for (int kt = 0; kt < ntiles; ++kt) {
    // stage kt+1 (clamped dummy on last iter keeps vmcnt accounting uniform)
    const int nkt = (kt + 1 < ntiles) ? kt + 1 : ntiles - 1;
    const int nbuf = (buf == 2) ? 0 : buf + 1;
    {
      const int kg = nkt * 64;
      #pragma unroll
      for (int j = 0; j < 2; ++j) {
        int r0 = wave * 16 + j * 8;
        load_lds16(kb  + (size_t)(kg + r0 + drow) * 64 + dch * 8, &Ks[nbuf][r0 * 64]);
        load_lds16(vtb + (size_t)(r0 + drow) * 2048 + kg + dch * 8, &Vs[nbuf][r0 * 64]);
      }
    }
    asm volatile("" ::: "memory");
    __builtin_amdgcn_s_waitcnt(0x0F74);   // vmcnt(4): tile kt's 4 DMAs done; kt+1 in flight
    __builtin_amdgcn_s_barrier();
    asm volatile("" ::: "memory");

    const bool actA = (kt <= tA);

    // ---- S^T = K Q^T : D[m=key][n=qrow] (A=K-frag, B=Q-frag) ----
    bf16x8 kf[4][2];
    #pragma unroll
    for (int nt = 0; nt < 4; ++nt) {
      kf[nt][0] = *reinterpret_cast<const bf16x8*>(&Ks[buf][(nt * 16 + L) * 64 + fo0]);
      kf[nt][1] = *reinterpret_cast<const bf16x8*>(&Ks[buf][(nt * 16 + L) * 64 + fo1]);
    }

    f32x4 sB[4] = {};
    #pragma unroll
    for (int nt = 0; nt < 4; ++nt) {
      sB[nt] = __builtin_amdgcn_mfma_f32_16x16x32_bf16(kf[nt][0], qfB[0], sB[nt], 0, 0, 0);
      sB[nt] = __builtin_amdgcn_mfma_f32_16x16x32_bf16(kf[nt][1], qfB[1], sB[nt], 0, 0, 0);
    }
    if (kt == tB) {  // diagonal mask: key > qrow -> -inf
      #pragma unroll
      for (int nt = 0; nt < 4; ++nt) {
        int key0 = kt * 64 + nt * 16 + quad * 4;
        int qr = rowB0 + L;
        #pragma unroll
        for (int r = 0; r < 4; ++r)
          if (key0 + r > qr) sB[nt][r] = -3.0e38f;
      }
    }
    #pragma unroll
    for (int nt = 0; nt < 4; ++nt) {
      float p0 = exp2f(sB[nt][0]), p1 = exp2f(sB[nt][1]);
      float p2 = exp2f(sB[nt][2]), p3 = exp2f(sB[nt][3]);
      rsB += (p0 + p1) + (p2 + p3);
      uint2 pk;
      pk.x = pkbf(p0, p1);
      pk.y = pkbf(p2, p3);
      *reinterpret_cast<uint2*>(&Ps[wave][16 + L][nt * 16 + quad * 4]) = pk;
    }

    if (actA) {
      f32x4 sA[4] = {};
      #pragma unroll
      for (int nt = 0; nt < 4; ++nt) {
        sA[nt] = __builtin_amdgcn_mfma_f32_16x16x32_bf16(kf[nt][0], qfA[0], sA[nt], 0, 0, 0);
        sA[nt] = __builtin_amdgcn_mfma_f32_16x16x32_bf16(kf[nt][1], qfA[1], sA[nt], 0, 0, 0);
      }
      if (kt == tA) {
        #pragma unroll
        for (int nt = 0; nt < 4; ++nt) {
          int key0 = kt * 64 + nt * 16 + quad * 4;
          int qr = rowA0 + L;
          #pragma unroll
          for (int r = 0; r < 4; ++r)
            if (key0 + r > qr) sA[nt][r] = -3.0e38f;
        }
      }
      #pragma unroll
      for (int nt = 0; nt < 4; ++nt) {
        float p0 = exp2f(sA[nt][0]), p1 = exp2f(sA[nt][1]);
        float p2 = exp2f(sA[nt][2]), p3 = exp2f(sA[nt][3]);
        rsA += (p0 + p1) + (p2 + p3);
        uint2 pk;
        pk.x = pkbf(p0, p1);
        pk.y = pkbf(p2, p3);
        *reinterpret_cast<uint2*>(&Ps[wave][L][nt * 16 + quad * 4]) = pk;
      }
    }

    // ---- O += P V ----  (P in A-layout directly from Ps[qrow][key])
    bf16x8 vf[4][2];
    #pragma unroll
    for (int nt = 0; nt < 4; ++nt) {
      vf[nt][0] = *reinterpret_cast<const bf16x8*>(&Vs[buf][(nt * 16 + L) * 64 + fo0]);
      vf[nt][1] = *reinterpret_cast<const bf16x8*>(&Vs[buf][(nt * 16 + L) * 64 + fo1]);
    }
    bf16x8 pb0 = *reinterpret_cast<const bf16x8*>(&Ps[wave][16 + L][quad * 8]);
    bf16x8 pb1 = *reinterpret_cast<const bf16x8*>(&Ps[wave][16 + L][32 + quad * 8]);
    #pragma unroll
    for (int nt = 0; nt < 4; ++nt) {
      oB[nt] = __builtin_amdgcn_mfma_f32_16x16x32_bf16(pb0, vf[nt][0], oB[nt], 0, 0, 0);
      oB[nt] = __builtin_amdgcn_mfma_f32_16x16x32_bf16(pb1, vf[nt][1], oB[nt], 0, 0, 0);
    }
    if (actA) {
      bf16x8 pa0 = *reinterpret_cast<const bf16x8*>(&Ps[wave][L][quad * 8]);
      bf16x8 pa1 = *reinterpret_cast<const bf16x8*>(&Ps[wave][L][32 + quad * 8]);
      #pragma unroll
      for (int nt = 0; nt < 4; ++nt) {
        oA[nt] = __builtin_amdgcn_mfma_f32_16x16x32_bf16(pa0, vf[nt][0], oA[nt], 0, 0, 0);
        oA[nt] = __builtin_amdgcn_mfma_f32_16x16x32_bf16(pa1, vf[nt][1], oA[nt], 0, 0, 0);
      }
    }
    buf = nbuf;
  }

  // ---- epilogue: reduce l across quads (rows live on L), fetch per-output-row via shfl ----
  float a = rsA; a += __shfl_xor(a, 16, 64); a += __shfl_xor(a, 32, 64);
  float b2 = rsB; b2 += __shfl_xor(b2, 16, 64); b2 += __shfl_xor(b2, 32, 64);
  float invA[4], invB[4];
  #pragma unroll
  for (int r = 0; r < 4; ++r) {
    invA[r] = 1.0f / __shfl(a, quad * 4 + r, 64);
    invB[r] = 1.0f / __shfl(b2, quad * 4 + r, 64);
  }
  const int bb = bh >> 4, hh = bh & 15;
  #pragma unroll
  for (int nt = 0; nt < 4; ++nt)
    #pragma unroll
    for (int r = 0; r < 4; ++r) {
      int rA = rowA0 + quad * 4 + r;
      int rB = rowB0 + quad * 4 + r;
      int col = hh * 64 + nt * 16 + L;
      y[((size_t)bb * 2048 + rA) * 1024 + col] = f2bf(oA[nt][r] * invA[r]);
      y[((size_t)bb * 2048 + rB) * 1024 + col] = f2bf(oB[nt][r] * invB[r]);
    }
  // drain outstanding dummy DMAs before LDS dealloc at wave end
  __builtin_amdgcn_s_waitcnt(0);
}

extern "C" void kernel_launch(void* const* d_in, const int* in_sizes, int n_in,
                              void* d_out, int out_size, void* d_ws, size_t ws_size,
                              hipStream_t stream) {
  const float* x      = (const float*)d_in[0];  // [2,2048,1024]
  const float* w_attn = (const float*)d_in[1];  // [1024,3072]
  const float* b_attn = (const float*)d_in[2];  // [3072]
  const float* w_proj = (const float*)d_in[3];  // [1024,1024]
  const float* b_proj = (const float*)d_in[4];  // [1024]
  float* out = (float*)d_out;                   // [2,2048,1024] fp32

  unsigned short* ws = (unsigned short*)d_ws;
  unsigned short* xb     = ws;                    //  4194304 [4096,1024]
  unsigned short* wattnT = xb + 4194304;          //  3145728 [3072,1024]
  unsigned short* wprojT = wattnT + 3145728;      //  1048576 [1024,1024]
  unsigned short* qkv    = wprojT + 1048576;      // 12582912 [3][32][2048][64] (v unused)
  unsigned short* yb     = qkv + 12582912;        //  4194304 [4096,1024]
  unsigned short* vt     = yb + 4194304;          //  4194304 [32][64][2048]

  cast_bf16_kernel<<<4096, 256, 0, stream>>>(x, xb, 1048576);
  transpose_cast_kernel<<<dim3(96, 32), dim3(32, 8), 0, stream>>>(w_attn, wattnT, 1024, 3072);
  transpose_cast_kernel<<<dim3(32, 32), dim3(32, 8), 0, stream>>>(w_proj, wprojT, 1024, 1024);

  // QKV: M=4096, N=3072, K=1024 (v transposed into vt in-epilogue)
  gemm_bt_kernel<<<dim3(24, 32), 256, 0, stream>>>(xb, wattnT, b_attn, qkv, vt, 4096, 3072, 1024, 1);
  // attention (fold-balanced, XCD-grouped, pipelined)
  attn_kernel<<<dim3(512), 256, 0, stream>>>(qkv, vt, yb);
  // proj: M=4096, N=1024, K=1024
  gemm_bt_kernel<<<dim3(8, 32), 256, 0, stream>>>(yb, wprojT, b_proj, out, nullptr, 4096, 1024, 1024, 0);
}